// Round 11
// baseline (2922.445 us; speedup 1.0000x reference)
//
#include <hip/hip_runtime.h>
#include <hip/hip_cooperative_groups.h>

namespace cg = cooperative_groups;

#define B_   32
#define HW_  196
#define C_   512
#define M_   (B_*HW_)    // 6272
#define HID_ 128
#define NBLK 18
#define GRID 784

typedef _Float16 f16;
typedef _Float16 f16x4 __attribute__((ext_vector_type(4)));
typedef _Float16 f16x8 __attribute__((ext_vector_type(8)));
typedef float    f32x4 __attribute__((ext_vector_type(4)));

__device__ __forceinline__ float gelu_f(float x) {
    float t = tanhf(0.7978845608028654f * (x + 0.044715f * x * x * x));
    return 0.5f * x * (1.0f + t);
}

// async global->LDS, 16B per lane; LDS dest = wave-uniform base + lane*16
__device__ __forceinline__ void gl16(const void* g, void* l) {
    __builtin_amdgcn_global_load_lds((const __attribute__((address_space(1))) unsigned*)g,
                                     (__attribute__((address_space(3))) unsigned*)l, 16, 0, 0);
}

struct PtrTab { const f16* in[NBLK]; f16* out[NBLK]; };

// ============================================================================
// Cooperative full-chain kernel. Exact r6 GEMM geometry (the 385us best):
// 64x64x64 tile, 4 waves 2x2, 2-buf 32KB drain loop, XOR-swizzled gl16 staging,
// chunked-XCD swizzle. Kernel boundaries replaced by grid.sync(); conv_w/conv_x
// distributed prologue; gate (32 blocks) + routed (784 blocks x 512 vecs = NB/8
// exactly) as in-kernel phases. 33280B LDS -> 4 blocks/CU, 784 co-resident.
// ============================================================================
#define BM 64
#define BN 64
#define BK 64
#define NKT (C_ / BK)   // 8
__global__ __launch_bounds__(256, 4) void chain_kernel(
    const float* __restrict__ x, const float* __restrict__ blockw,
    const float* __restrict__ ball,
    const float* __restrict__ fc1w, const float* __restrict__ fc1b,
    const float* __restrict__ fc2w, const float* __restrict__ fc2b,
    const float* __restrict__ gammas,
    f16* __restrict__ Wt, f16* __restrict__ P1,
    const f16* __restrict__ A0, const f16* __restrict__ A1, const f16* __restrict__ A2,
    float* __restrict__ pooled, float* __restrict__ gates,
    float* __restrict__ out, PtrTab tab)
{
    cg::grid_group gg = cg::this_grid();
    __shared__ __align__(16) unsigned char ldsraw[33280];
    f16 (*As)[BM * BK] = reinterpret_cast<f16 (*)[BM * BK]>(ldsraw);          // 2 x 8 KB
    f16 (*Ws)[BN * BK] = reinterpret_cast<f16 (*)[BN * BK]>(ldsraw + 16384);  // 2 x 8 KB
    float (*spool)[BN] = reinterpret_cast<float (*)[BN]>(ldsraw + 32768);     // 512 B

    const int bid = blockIdx.x, tid = threadIdx.x;
    const int wave = tid >> 6, lane = tid & 63;
    const int m15 = lane & 15, q = lane >> 4;
    const int wr = wave >> 1, wc = wave & 1;

    // ---- prologue A: x fp32 -> fp16 (+ zero pooled), 3136 jobs / 784 blocks = 4 ----
    #pragma unroll
    for (int jj = 0; jj < 4; ++jj) {
        int job = bid + jj * GRID;
        int i = job * 256 + tid;
        if (job < 64) pooled[i] = 0.f;
        float4 a = ((const float4*)x)[i];
        f16x4 o; o[0] = (f16)a.x; o[1] = (f16)a.y; o[2] = (f16)a.z; o[3] = (f16)a.w;
        ((f16x4*)P1)[i] = o;
    }
    // ---- prologue B: weights fp32 [k][n] -> fp16 [n][k], 1152 tile-jobs ----
    {
        f16 (*sh)[72] = reinterpret_cast<f16 (*)[72]>(ldsraw);
        for (int job = bid; job < 8 * 8 * NBLK; job += GRID) {
            int blkw = job >> 6, rem = job & 63;
            int k0 = (rem >> 3) << 6, n0 = (rem & 7) << 6;
            const float* Wb = blockw + (size_t)blkw * C_ * C_;
            __syncthreads();   // protect sh reuse across jobs
            #pragma unroll
            for (int i = 0; i < 4; ++i) {
                int s = tid + i * 256, r = s >> 4, c4 = (s & 15) << 2;
                float4 v = *(const float4*)&Wb[(size_t)(k0 + r) * C_ + n0 + c4];
                sh[r][c4 + 0] = (f16)v.x; sh[r][c4 + 1] = (f16)v.y;
                sh[r][c4 + 2] = (f16)v.z; sh[r][c4 + 3] = (f16)v.w;
            }
            __syncthreads();
            #pragma unroll
            for (int i = 0; i < 2; ++i) {
                int s = tid + i * 256, r = s >> 3, c8 = (s & 7) << 3;
                f16x8 o;
                #pragma unroll
                for (int j = 0; j < 8; ++j) o[j] = sh[c8 + j][r];
                *(f16x8*)&Wt[(size_t)blkw * C_ * C_ + (size_t)(n0 + r) * C_ + k0 + c8] = o;
            }
        }
    }
    gg.sync();   // Wt, P1, pooled ready

    // ---- blk-invariant GEMM geometry (exact r6) ----
    const int lin  = bid;                              // 1-D == r6's x+98y order
    const int tile = (lin & 7) * 98 + (lin >> 3);      // chunked-XCD (bijective 784=8*98)
    const int rb   = tile >> 3, cb = tile & 7;
    const int row0 = rb * BM, col0 = cb * BN;
    const int srow = lane >> 3;
    const int scol = ((lane & 7) ^ (srow & 7)) << 3;   // halfs
    size_t aoff[2], woff[2];
    f16* aDst[2][2]; f16* wDst[2][2];
    #pragma unroll
    for (int i = 0; i < 2; ++i) {
        int ch = wave * 2 + i;
        aoff[i] = (size_t)(row0 + ch * 8 + srow) * C_ + scol;
        woff[i] = (size_t)(col0 + ch * 8 + srow) * C_ + scol;
        aDst[0][i] = &As[0][ch * 512]; aDst[1][i] = &As[1][ch * 512];
        wDst[0][i] = &Ws[0][ch * 512]; wDst[1][i] = &Ws[1][ch * 512];
    }
    const int bA = row0 / HW_;

    #pragma unroll 1
    for (int blk = 0; blk < NBLK; ++blk) {
        const f16* Ain = tab.in[blk];
        f16* Cout = tab.out[blk];
        const f16* Wbb = Wt + (size_t)blk * C_ * C_;
        const int t = (blk == 11) ? 0 : (blk == 14) ? 1 : (blk == 17) ? 2 : -1;
        const bool doPool = (t >= 0);

        f32x4 acc[2][2];
        #pragma unroll
        for (int i = 0; i < 2; ++i)
            #pragma unroll
            for (int j = 0; j < 2; ++j) acc[i][j] = (f32x4)0.f;

        // prefetch tile 0 -> buf 0
        #pragma unroll
        for (int i = 0; i < 2; ++i) {
            gl16(Ain + aoff[i], aDst[0][i]);
            gl16(Wbb + woff[i], wDst[0][i]);
        }
        #pragma unroll
        for (int kt = 0; kt < NKT; ++kt) {
            __syncthreads();   // drains this tile's loads + syncs buffer reuse
            int cur = kt & 1;
            if (kt + 1 < NKT) {
                int nxt = cur ^ 1, koff = (kt + 1) * BK;
                #pragma unroll
                for (int i = 0; i < 2; ++i) {
                    gl16(Ain + aoff[i] + koff, aDst[nxt][i]);
                    gl16(Wbb + woff[i] + koff, wDst[nxt][i]);
                }
            }
            const f16* Ab = &As[cur][0];
            const f16* Bb = &Ws[cur][0];
            #pragma unroll
            for (int kk = 0; kk < BK; kk += 32) {
                f16x8 af[2], bf[2];
                #pragma unroll
                for (int i = 0; i < 2; ++i) {
                    int r = wr * 32 + i * 16 + m15;
                    int c = (kk >> 3) + q;
                    af[i] = *(const f16x8*)&Ab[r * 64 + ((c ^ (r & 7)) << 3)];
                }
                #pragma unroll
                for (int j = 0; j < 2; ++j) {
                    int r = wc * 32 + j * 16 + m15;
                    int c = (kk >> 3) + q;
                    bf[j] = *(const f16x8*)&Bb[r * 64 + ((c ^ (r & 7)) << 3)];
                }
                __builtin_amdgcn_s_setprio(1);
                #pragma unroll
                for (int i = 0; i < 2; ++i)
                    #pragma unroll
                    for (int j = 0; j < 2; ++j)
                        acc[i][j] = __builtin_amdgcn_mfma_f32_16x16x32_f16(af[i], bf[j], acc[i][j], 0, 0, 0);
                __builtin_amdgcn_s_setprio(0);
            }
        }

        // epilogue (r6): C/D layout col=lane&15, row=quad*4+reg
        if (doPool) {
            if (tid < 2 * BN) ((float*)spool)[tid] = 0.f;
            __syncthreads();
        }
        float ps[2][2] = {{0.f, 0.f}, {0.f, 0.f}};
        float bcol[2];
        #pragma unroll
        for (int j = 0; j < 2; ++j) bcol[j] = ball[blk * C_ + col0 + wc * 32 + j * 16 + m15];
        #pragma unroll
        for (int i = 0; i < 2; ++i) {
            #pragma unroll
            for (int r = 0; r < 4; ++r) {
                int row = row0 + wr * 32 + i * 16 + q * 4 + r;
                int slot = (row / HW_) - bA;
                #pragma unroll
                for (int j = 0; j < 2; ++j) {
                    int col = col0 + wc * 32 + j * 16 + m15;
                    float v = gelu_f(acc[i][j][r] + bcol[j]);
                    Cout[(size_t)row * C_ + col] = (f16)v;
                    if (doPool) ps[slot & 1][j] += v;
                }
            }
        }
        if (doPool) {
            #pragma unroll
            for (int s = 0; s < 2; ++s)
                #pragma unroll
                for (int j = 0; j < 2; ++j)
                    atomicAdd(&spool[s][wc * 32 + j * 16 + m15], ps[s][j]);
            __syncthreads();
            if (tid < 2 * BN) {
                int slot = tid >> 6, colt = tid & 63;
                int b = bA + slot;
                int lastb = (row0 + BM - 1) / HW_;
                if (b <= lastb)
                    atomicAdd(&pooled[(size_t)b * C_ + col0 + colt], spool[slot][colt]);
            }
        }
        gg.sync();   // output + pooled visible grid-wide

        if (t >= 0) {
            // ---- gate phase: blocks 0..31 (b = bid) ----
            if (bid < B_) {
                float* sp  = (float*)ldsraw;         // 512
                float* sh2 = sp + C_;                // 2*128
                float* shh = sh2 + 2 * HID_;         // 128
                const int b = bid;
                float2 pv = *(const float2*)&pooled[b * C_ + 2 * tid];
                sp[2 * tid]     = pv.x * (1.f / 196.f);
                sp[2 * tid + 1] = pv.y * (1.f / 196.f);
                *(float2*)&pooled[b * C_ + 2 * tid] = make_float2(0.f, 0.f);
                __syncthreads();
                {
                    int half = tid >> 7, hh = tid & 127;
                    const float* w = fc1w + (size_t)t * C_ * HID_ + hh;
                    float s = 0.f;
                    int c0 = half * 256;
                    for (int c = c0; c < c0 + 256; ++c) s += sp[c] * w[(size_t)c * HID_];
                    sh2[half * HID_ + hh] = s;
                }
                __syncthreads();
                if (tid < HID_) shh[tid] = gelu_f(sh2[tid] + sh2[HID_ + tid] + fc1b[t * HID_ + tid]);
                __syncthreads();
                #pragma unroll
                for (int cc = 0; cc < 2; ++cc) {
                    int c = tid + cc * 256;
                    const float* w2 = fc2w + (size_t)t * HID_ * (3 * C_) + c;
                    float l0 = fc2b[t * 3 * C_ + c];
                    float l1 = fc2b[t * 3 * C_ + C_ + c];
                    float l2 = fc2b[t * 3 * C_ + 2 * C_ + c];
                    for (int j = 0; j < HID_; ++j) {
                        float h = shh[j];
                        const float* r = w2 + (size_t)j * 3 * C_;
                        l0 += h * r[0]; l1 += h * r[C_]; l2 += h * r[2 * C_];
                    }
                    float m  = fmaxf(l0, fmaxf(l1, l2));
                    float e0 = expf(l0 - m), e1 = expf(l1 - m), e2 = expf(l2 - m);
                    float inv = 1.f / (e0 + e1 + e2);
                    gates[(size_t)b * 3 * C_ + c]          = e0 * inv;
                    gates[(size_t)b * 3 * C_ + C_ + c]     = e1 * inv;
                    gates[(size_t)b * 3 * C_ + 2 * C_ + c] = e2 * inv;
                }
            }
            gg.sync();   // gates visible (also block-syncs LDS reuse)

            // ---- routed phase: 784 blocks x 512 vecs = NB/8 exactly ----
            {
                f16* nx = Cout;
                float gamma = gammas[t];
                #pragma unroll
                for (int k = 0; k < 2; ++k) {
                    int v = bid * 512 + k * 256 + tid;
                    int idx = v * 8;
                    int c = idx & (C_ - 1);
                    int b = idx / (HW_ * C_);
                    const float* g = gates + (size_t)b * 3 * C_ + c;
                    f16x8 xn = ((const f16x8*)nx)[v];
                    f16x8 x0 = ((const f16x8*)A0)[v];
                    f16x8 x1 = ((const f16x8*)A1)[v];
                    f16x8 x2 = ((const f16x8*)A2)[v];
                    float r[8];
                    #pragma unroll
                    for (int e = 0; e < 8; ++e)
                        r[e] = (float)xn[e] + gamma * (g[e] * (float)x0[e]
                               + g[C_ + e] * (float)x1[e] + g[2 * C_ + e] * (float)x2[e]);
                    if (t == 2) {
                        float4* o = (float4*)&out[idx];
                        o[0] = make_float4(r[0], r[1], r[2], r[3]);
                        o[1] = make_float4(r[4], r[5], r[6], r[7]);
                    } else {
                        f16x8 o;
                        #pragma unroll
                        for (int e = 0; e < 8; ++e) o[e] = (f16)r[e];
                        ((f16x8*)nx)[v] = o;
                    }
                }
            }
            if (t < 2) gg.sync();   // routed nx visible before next GEMM stages it
        }
    }
}

// ============================================================================
// Fallback path: exact r6 multi-launch kernels (385us) — used if cooperative
// launch is rejected (capture-unsupported / too-large).
// ============================================================================
__global__ __launch_bounds__(256) void conv_w(const float* __restrict__ W,
                                              f16* __restrict__ Wt) {
    __shared__ f16 sh[64][72];
    const int blk = blockIdx.z, k0 = blockIdx.x * 64, n0 = blockIdx.y * 64;
    const int tid = threadIdx.x;
    const float* Wb = W + (size_t)blk * C_ * C_;
    #pragma unroll
    for (int i = 0; i < 4; ++i) {
        int s = tid + i * 256, r = s >> 4, c4 = (s & 15) << 2;
        float4 v = *(const float4*)&Wb[(size_t)(k0 + r) * C_ + n0 + c4];
        sh[r][c4 + 0] = (f16)v.x; sh[r][c4 + 1] = (f16)v.y;
        sh[r][c4 + 2] = (f16)v.z; sh[r][c4 + 3] = (f16)v.w;
    }
    __syncthreads();
    #pragma unroll
    for (int i = 0; i < 2; ++i) {
        int s = tid + i * 256, r = s >> 3, c8 = (s & 7) << 3;
        f16x8 o;
        #pragma unroll
        for (int j = 0; j < 8; ++j) o[j] = sh[c8 + j][r];
        *(f16x8*)&Wt[(size_t)blk * C_ * C_ + (size_t)(n0 + r) * C_ + k0 + c8] = o;
    }
}

__global__ __launch_bounds__(256) void conv_x(const float* __restrict__ in,
                                              f16* __restrict__ out,
                                              float* __restrict__ pooled) {
    int i = blockIdx.x * 256 + threadIdx.x;
    if (blockIdx.x < 64) pooled[i] = 0.f;
    float4 a = ((const float4*)in)[i];
    f16x4 o; o[0] = (f16)a.x; o[1] = (f16)a.y; o[2] = (f16)a.z; o[3] = (f16)a.w;
    ((f16x4*)out)[i] = o;
}

__global__ __launch_bounds__(256, 4) void gemm_f16(
    const f16* __restrict__ A, const f16* __restrict__ Wt,
    const float* __restrict__ ball, int blk, f16* __restrict__ out,
    float* __restrict__ pooled)
{
    __shared__ f16 As[2][BM * BK];
    __shared__ f16 Ws[2][BN * BK];
    __shared__ float spool[2][BN];
    const int tid = threadIdx.x;
    const int wave = tid >> 6, lane = tid & 63;
    const int m15 = lane & 15, q = lane >> 4;
    const int wr = wave >> 1, wc = wave & 1;
    const int lin  = blockIdx.x + 98 * blockIdx.y;
    const int tile = (lin & 7) * 98 + (lin >> 3);
    const int rb   = tile >> 3, cb = tile & 7;
    const int row0 = rb * BM, col0 = cb * BN;
    const f16* Wb = Wt + (size_t)blk * C_ * C_;
    const float* bias = ball + (size_t)blk * C_;
    const int srow = lane >> 3;
    const int scol = ((lane & 7) ^ (srow & 7)) << 3;
    const f16* aSrc[2]; const f16* wSrc[2];
    f16* aDst[2][2]; f16* wDst[2][2];
    #pragma unroll
    for (int i = 0; i < 2; ++i) {
        int ch = wave * 2 + i;
        aSrc[i] = A  + (size_t)(row0 + ch * 8 + srow) * C_ + scol;
        wSrc[i] = Wb + (size_t)(col0 + ch * 8 + srow) * C_ + scol;
        aDst[0][i] = &As[0][ch * 512]; aDst[1][i] = &As[1][ch * 512];
        wDst[0][i] = &Ws[0][ch * 512]; wDst[1][i] = &Ws[1][ch * 512];
    }
    f32x4 acc[2][2];
    #pragma unroll
    for (int i = 0; i < 2; ++i)
        #pragma unroll
        for (int j = 0; j < 2; ++j) acc[i][j] = (f32x4)0.f;
    #pragma unroll
    for (int i = 0; i < 2; ++i) { gl16(aSrc[i], aDst[0][i]); gl16(wSrc[i], wDst[0][i]); }
    #pragma unroll
    for (int kt = 0; kt < NKT; ++kt) {
        __syncthreads();
        int cur = kt & 1;
        if (kt + 1 < NKT) {
            int nxt = cur ^ 1, koff = (kt + 1) * BK;
            #pragma unroll
            for (int i = 0; i < 2; ++i) {
                gl16(aSrc[i] + koff, aDst[nxt][i]);
                gl16(wSrc[i] + koff, wDst[nxt][i]);
            }
        }
        const f16* Ab = &As[cur][0];
        const f16* Bb = &Ws[cur][0];
        #pragma unroll
        for (int kk = 0; kk < BK; kk += 32) {
            f16x8 af[2], bf[2];
            #pragma unroll
            for (int i = 0; i < 2; ++i) {
                int r = wr * 32 + i * 16 + m15;
                int c = (kk >> 3) + q;
                af[i] = *(const f16x8*)&Ab[r * 64 + ((c ^ (r & 7)) << 3)];
            }
            #pragma unroll
            for (int j = 0; j < 2; ++j) {
                int r = wc * 32 + j * 16 + m15;
                int c = (kk >> 3) + q;
                bf[j] = *(const f16x8*)&Bb[r * 64 + ((c ^ (r & 7)) << 3)];
            }
            __builtin_amdgcn_s_setprio(1);
            #pragma unroll
            for (int i = 0; i < 2; ++i)
                #pragma unroll
                for (int j = 0; j < 2; ++j)
                    acc[i][j] = __builtin_amdgcn_mfma_f32_16x16x32_f16(af[i], bf[j], acc[i][j], 0, 0, 0);
            __builtin_amdgcn_s_setprio(0);
        }
    }
    const bool doPool = (pooled != nullptr);
    if (doPool) {
        if (tid < 2 * BN) ((float*)spool)[tid] = 0.f;
        __syncthreads();
    }
    const int bA = row0 / HW_;
    float ps[2][2] = {{0.f, 0.f}, {0.f, 0.f}};
    float bcol[2];
    #pragma unroll
    for (int j = 0; j < 2; ++j) bcol[j] = bias[col0 + wc * 32 + j * 16 + m15];
    #pragma unroll
    for (int i = 0; i < 2; ++i) {
        #pragma unroll
        for (int r = 0; r < 4; ++r) {
            int row = row0 + wr * 32 + i * 16 + q * 4 + r;
            int slot = (row / HW_) - bA;
            #pragma unroll
            for (int j = 0; j < 2; ++j) {
                int col = col0 + wc * 32 + j * 16 + m15;
                float v = gelu_f(acc[i][j][r] + bcol[j]);
                out[(size_t)row * C_ + col] = (f16)v;
                if (doPool) ps[slot & 1][j] += v;
            }
        }
    }
    if (doPool) {
        #pragma unroll
        for (int s = 0; s < 2; ++s)
            #pragma unroll
            for (int j = 0; j < 2; ++j)
                atomicAdd(&spool[s][wc * 32 + j * 16 + m15], ps[s][j]);
        __syncthreads();
        if (tid < 2 * BN) {
            int slot = tid >> 6, colt = tid & 63;
            int b = bA + slot;
            int lastb = (row0 + BM - 1) / HW_;
            if (b <= lastb)
                atomicAdd(&pooled[(size_t)b * C_ + col0 + colt], spool[slot][colt]);
        }
    }
}

__global__ __launch_bounds__(256) void gate_kernel(float* __restrict__ pooled,
    const float* __restrict__ fc1w, const float* __restrict__ fc1b,
    const float* __restrict__ fc2w, const float* __restrict__ fc2b,
    int t, float* __restrict__ gates)
{
    __shared__ float sp[C_];
    __shared__ float sh2[2][HID_];
    __shared__ float sh[HID_];
    const int b = blockIdx.x, tid = threadIdx.x;
    float2 pv = *(const float2*)&pooled[b * C_ + 2 * tid];
    sp[2 * tid]     = pv.x * (1.f / 196.f);
    sp[2 * tid + 1] = pv.y * (1.f / 196.f);
    *(float2*)&pooled[b * C_ + 2 * tid] = make_float2(0.f, 0.f);
    __syncthreads();
    {
        int half = tid >> 7, hh = tid & 127;
        const float* w = fc1w + (size_t)t * C_ * HID_ + hh;
        float s = 0.f;
        int c0 = half * 256;
        for (int c = c0; c < c0 + 256; ++c) s += sp[c] * w[(size_t)c * HID_];
        sh2[half][hh] = s;
    }
    __syncthreads();
    if (tid < HID_) sh[tid] = gelu_f(sh2[0][tid] + sh2[1][tid] + fc1b[t * HID_ + tid]);
    __syncthreads();
    #pragma unroll
    for (int cc = 0; cc < 2; ++cc) {
        int c = tid + cc * 256;
        const float* w2 = fc2w + (size_t)t * HID_ * (3 * C_) + c;
        float l0 = fc2b[t * 3 * C_ + c];
        float l1 = fc2b[t * 3 * C_ + C_ + c];
        float l2 = fc2b[t * 3 * C_ + 2 * C_ + c];
        for (int j = 0; j < HID_; ++j) {
            float h = sh[j];
            const float* r = w2 + (size_t)j * 3 * C_;
            l0 += h * r[0]; l1 += h * r[C_]; l2 += h * r[2 * C_];
        }
        float m  = fmaxf(l0, fmaxf(l1, l2));
        float e0 = expf(l0 - m), e1 = expf(l1 - m), e2 = expf(l2 - m);
        float inv = 1.f / (e0 + e1 + e2);
        gates[(size_t)b * 3 * C_ + c]          = e0 * inv;
        gates[(size_t)b * 3 * C_ + C_ + c]     = e1 * inv;
        gates[(size_t)b * 3 * C_ + 2 * C_ + c] = e2 * inv;
    }
}

__global__ __launch_bounds__(256) void routed_add_kernel(f16* __restrict__ nx,
    const f16* __restrict__ a0, const f16* __restrict__ a1, const f16* __restrict__ a2,
    const float* __restrict__ gates, const float* __restrict__ gammas, int t,
    float* __restrict__ outf)
{
    int v = blockIdx.x * 256 + threadIdx.x;
    int idx = v * 8;
    int c = idx & (C_ - 1);
    int b = idx / (HW_ * C_);
    const float* g = gates + (size_t)b * 3 * C_ + c;
    float gamma = gammas[t];
    f16x8 xn = ((const f16x8*)nx)[v];
    f16x8 x0 = ((const f16x8*)a0)[v];
    f16x8 x1 = ((const f16x8*)a1)[v];
    f16x8 x2 = ((const f16x8*)a2)[v];
    float r[8];
    #pragma unroll
    for (int e = 0; e < 8; ++e)
        r[e] = (float)xn[e] + gamma * (g[e] * (float)x0[e] + g[C_ + e] * (float)x1[e]
                                       + g[2 * C_ + e] * (float)x2[e]);
    if (outf) {
        float4* o = (float4*)&outf[idx];
        o[0] = make_float4(r[0], r[1], r[2], r[3]);
        o[1] = make_float4(r[4], r[5], r[6], r[7]);
    } else {
        f16x8 o;
        #pragma unroll
        for (int e = 0; e < 8; ++e) o[e] = (f16)r[e];
        ((f16x8*)nx)[v] = o;
    }
}

extern "C" void kernel_launch(void* const* d_in, const int* in_sizes, int n_in,
                              void* d_out, int out_size, void* d_ws, size_t ws_size,
                              hipStream_t stream)
{
    const float* x      = (const float*)d_in[0];
    const float* blockw = (const float*)d_in[1];
    const float* blockb = (const float*)d_in[2];
    const float* fc1w   = (const float*)d_in[3];
    const float* fc1b   = (const float*)d_in[4];
    const float* fc2w   = (const float*)d_in[5];
    const float* fc2b   = (const float*)d_in[6];
    const float* gammas = (const float*)d_in[7];
    float* out = (float*)d_out;

    const size_t NB = (size_t)M_ * C_;
    f16* Wt = (f16*)d_ws;
    f16* P0 = Wt + (size_t)NBLK * C_ * C_;
    f16* P1 = P0 + NB;
    f16* A0 = P0 + 2 * NB;
    f16* A1 = P0 + 3 * NB;
    f16* A2 = P0 + 4 * NB;
    float* pooled = (float*)(P0 + 5 * NB);
    float* gates  = pooled + B_ * C_;

    PtrTab tab = {
        {P1, P0, A0, P0, P1, A1, P0, P1, P0, P1, A2, P0, P1, P0, P1, P0, P1, P0},
        {P0, A0, P0, P1, A1, P0, P1, P0, P1, A2, P0, P1, P0, P1, P0, P1, P0, P1}
    };

    void* args[] = { (void*)&x, (void*)&blockw, (void*)&blockb,
                     (void*)&fc1w, (void*)&fc1b, (void*)&fc2w, (void*)&fc2b,
                     (void*)&gammas, (void*)&Wt, (void*)&P1,
                     (void*)&A0, (void*)&A1, (void*)&A2,
                     (void*)&pooled, (void*)&gates, (void*)&out, (void*)&tab };
    hipError_t err = hipLaunchCooperativeKernel((const void*)chain_kernel,
                                                dim3(GRID), dim3(256), args, 0, stream);
    if (err == hipSuccess) return;
    (void)hipGetLastError();   // clear, fall back to r6 multi-launch

    conv_w<<<dim3(8, 8, NBLK), 256, 0, stream>>>(blockw, Wt);
    conv_x<<<(int)(NB / 1024), 256, 0, stream>>>(x, P1, pooled);
    for (int i = 0; i < NBLK; ++i) {
        int t = (i == 11) ? 0 : (i == 14) ? 1 : (i == 17) ? 2 : -1;
        gemm_f16<<<dim3(M_ / BM, C_ / BN), 256, 0, stream>>>(
            tab.in[i], Wt, blockb, i, tab.out[i], (t >= 0) ? pooled : (float*)nullptr);
        if (t >= 0) {
            gate_kernel<<<B_, 256, 0, stream>>>(pooled, fc1w, fc1b, fc2w, fc2b, t, gates);
            routed_add_kernel<<<(int)(NB / 2048), 256, 0, stream>>>(
                tab.out[i], A0, A1, A2, gates, gammas, t,
                (t == 2) ? out : (float*)nullptr);
        }
    }
}

// Round 12
// 391.698 us; speedup vs baseline: 7.4610x; 7.4610x over previous
//
#include <hip/hip_runtime.h>

#define B_   32
#define HW_  196
#define C_   512
#define M_   (B_*HW_)    // 6272
#define HID_ 128
#define NBLK 18

typedef _Float16 f16;
typedef _Float16 f16x2 __attribute__((ext_vector_type(2)));
typedef _Float16 f16x4 __attribute__((ext_vector_type(4)));
typedef _Float16 f16x8 __attribute__((ext_vector_type(8)));
typedef float    f32x4 __attribute__((ext_vector_type(4)));

__device__ __forceinline__ float gelu_f(float x) {
    float t = tanhf(0.7978845608028654f * (x + 0.044715f * x * x * x));
    return 0.5f * x * (1.0f + t);
}

// async global->LDS, 16B per lane; LDS dest = wave-uniform base + lane*16
__device__ __forceinline__ void gl16(const void* g, void* l) {
    __builtin_amdgcn_global_load_lds((const __attribute__((address_space(1))) unsigned*)g,
                                     (__attribute__((address_space(3))) unsigned*)l, 16, 0, 0);
}

// ---------- weights: fp32 [blk][k][n] -> fp16 transposed [blk][n][k] ----------
__global__ __launch_bounds__(256) void conv_w(const float* __restrict__ W,
                                              f16* __restrict__ Wt) {
    __shared__ f16 sh[64][72];
    const int blk = blockIdx.z, k0 = blockIdx.x * 64, n0 = blockIdx.y * 64;
    const int tid = threadIdx.x;
    const float* Wb = W + (size_t)blk * C_ * C_;
    #pragma unroll
    for (int i = 0; i < 4; ++i) {
        int s = tid + i * 256, r = s >> 4, c4 = (s & 15) << 2;
        float4 v = *(const float4*)&Wb[(size_t)(k0 + r) * C_ + n0 + c4];
        sh[r][c4 + 0] = (f16)v.x; sh[r][c4 + 1] = (f16)v.y;
        sh[r][c4 + 2] = (f16)v.z; sh[r][c4 + 3] = (f16)v.w;
    }
    __syncthreads();
    #pragma unroll
    for (int i = 0; i < 2; ++i) {
        int s = tid + i * 256, r = s >> 3, c8 = (s & 7) << 3;
        f16x8 o;
        #pragma unroll
        for (int j = 0; j < 8; ++j) o[j] = sh[c8 + j][r];
        *(f16x8*)&Wt[(size_t)blk * C_ * C_ + (size_t)(n0 + r) * C_ + k0 + c8] = o;
    }
}

// ---------- x: fp32 -> fp16 (x4 vectorized); first 64 blocks also zero pooled ----------
__global__ __launch_bounds__(256) void conv_x(const float* __restrict__ in,
                                              f16* __restrict__ out,
                                              float* __restrict__ pooled) {
    int i = blockIdx.x * 256 + threadIdx.x;
    if (blockIdx.x < 64) pooled[i] = 0.f;   // 64*256 = 16384 = B_*C_
    float4 a = ((const float4*)in)[i];
    f16x4 o; o[0] = (f16)a.x; o[1] = (f16)a.y; o[2] = (f16)a.z; o[3] = (f16)a.w;
    ((f16x4*)out)[i] = o;
}

// ---------- MFMA GEMM: out = gelu(A[M,K]@W_blk[K,N] + b) [+ column-sum pooling] ----------
// 64x64x64 tile, 4 waves. Proven best (r6 = 385.3us): 2-buffer 32KB LDS drain
// loop -> 4 blocks/CU (16 waves), grid 784 all-resident, chunked-XCD swizzle.
// Exploration record (r7-r11): fused routing 405, BM128 418, BN32 446, counted
// BK32 pipeline 395, persistent 1214, cooperative grid.sync ~115us/sync = 2922.
// This structure is the measured floor of the launch-based chain.
#define BM 64
#define BN 64
#define BK 64
#define NKT (C_ / BK)   // 8
// LDS layout (halfs): tile[r][c-block] at r*64 + ((c ^ (r&7))<<3), r<64, c<8
__global__ __launch_bounds__(256, 4) void gemm_f16(
    const f16* __restrict__ A, const f16* __restrict__ Wt,
    const float* __restrict__ ball, int blk, f16* __restrict__ out,
    float* __restrict__ pooled)
{
    __shared__ f16 As[2][BM * BK];   // 2 x 8 KB
    __shared__ f16 Ws[2][BN * BK];   // 2 x 8 KB  -> 32 KB total, 4 blocks/CU
    __shared__ float spool[2][BN];   // per-batch-slot column sums (512 B)
    const int tid = threadIdx.x;
    const int wave = tid >> 6, lane = tid & 63;
    const int m15 = lane & 15, q = lane >> 4;
    const int wr = wave >> 1, wc = wave & 1;           // 2x2 wave grid, 32x32 tiles

    // chunked-XCD swizzle (bijective, 784 = 8*98)
    const int lin  = blockIdx.x + 98 * blockIdx.y;     // hw dispatch order
    const int tile = (lin & 7) * 98 + (lin >> 3);      // contiguous chunk per XCD
    const int rb   = tile >> 3, cb = tile & 7;
    const int row0 = rb * BM, col0 = cb * BN;

    const f16* Wb = Wt + (size_t)blk * C_ * C_;
    const float* bias = ball + (size_t)blk * C_;

    // staging: chunk ch = 8 rows x 64k (1KB). lane l loads row ch*8+(l>>3),
    // col-block (l&7)^(srow&7), landing at LDS base+l*16 = swizzled layout.
    const int srow = lane >> 3;
    const int scol = ((lane & 7) ^ (srow & 7)) << 3;   // halfs
    const f16* aSrc[2]; const f16* wSrc[2];
    f16* aDst[2][2]; f16* wDst[2][2];
    #pragma unroll
    for (int i = 0; i < 2; ++i) {
        int ch = wave * 2 + i;                          // 8 chunks cover 64 rows
        aSrc[i] = A  + (size_t)(row0 + ch * 8 + srow) * C_ + scol;
        wSrc[i] = Wb + (size_t)(col0 + ch * 8 + srow) * C_ + scol;
        aDst[0][i] = &As[0][ch * 512]; aDst[1][i] = &As[1][ch * 512];
        wDst[0][i] = &Ws[0][ch * 512]; wDst[1][i] = &Ws[1][ch * 512];
    }

    f32x4 acc[2][2];
    #pragma unroll
    for (int i = 0; i < 2; ++i)
        #pragma unroll
        for (int j = 0; j < 2; ++j) acc[i][j] = (f32x4)0.f;

    // prefetch tile 0 -> buf 0
    #pragma unroll
    for (int i = 0; i < 2; ++i) { gl16(aSrc[i], aDst[0][i]); gl16(wSrc[i], wDst[0][i]); }

    #pragma unroll
    for (int kt = 0; kt < NKT; ++kt) {
        __syncthreads();   // drains this tile's loads + syncs buffer reuse
        int cur = kt & 1;
        if (kt + 1 < NKT) {
            int nxt = cur ^ 1, koff = (kt + 1) * BK;
            #pragma unroll
            for (int i = 0; i < 2; ++i) {
                gl16(aSrc[i] + koff, aDst[nxt][i]);
                gl16(wSrc[i] + koff, wDst[nxt][i]);
            }
        }
        const f16* Ab = &As[cur][0];
        const f16* Bb = &Ws[cur][0];
        #pragma unroll
        for (int kk = 0; kk < BK; kk += 32) {
            f16x8 af[2], bf[2];
            #pragma unroll
            for (int i = 0; i < 2; ++i) {
                int r = wr * 32 + i * 16 + m15;
                int c = (kk >> 3) + q;
                af[i] = *(const f16x8*)&Ab[r * 64 + ((c ^ (r & 7)) << 3)];
            }
            #pragma unroll
            for (int j = 0; j < 2; ++j) {
                int r = wc * 32 + j * 16 + m15;
                int c = (kk >> 3) + q;
                bf[j] = *(const f16x8*)&Bb[r * 64 + ((c ^ (r & 7)) << 3)];
            }
            __builtin_amdgcn_s_setprio(1);
            #pragma unroll
            for (int i = 0; i < 2; ++i)
                #pragma unroll
                for (int j = 0; j < 2; ++j)
                    acc[i][j] = __builtin_amdgcn_mfma_f32_16x16x32_f16(af[i], bf[j], acc[i][j], 0, 0, 0);
            __builtin_amdgcn_s_setprio(0);
        }
    }

    // epilogue: C/D layout col=lane&15, row=quad*4+reg (HW-verified, dtype-indep)
    const bool doPool = (pooled != nullptr);
    if (doPool) {
        if (tid < 2 * BN) ((float*)spool)[tid] = 0.f;
        __syncthreads();
    }
    const int bA = row0 / HW_;                 // first batch this tile touches
    float ps[2][2] = {{0.f, 0.f}, {0.f, 0.f}}; // [batch-slot][j] partial sums
    float bcol[2];
    #pragma unroll
    for (int j = 0; j < 2; ++j) bcol[j] = bias[col0 + wc * 32 + j * 16 + m15];
    #pragma unroll
    for (int i = 0; i < 2; ++i) {
        #pragma unroll
        for (int r = 0; r < 4; ++r) {
            int rloc = wr * 32 + i * 16 + q * 4 + r;
            int row = row0 + rloc;
            int slot = (row / HW_) - bA;       // 0 or 1 (tile spans <= 2 batches)
            #pragma unroll
            for (int j = 0; j < 2; ++j) {
                int col = col0 + wc * 32 + j * 16 + m15;
                float v = gelu_f(acc[i][j][r] + bcol[j]);
                out[(size_t)row * C_ + col] = (f16)v;
                if (doPool) ps[slot & 1][j] += v;
            }
        }
    }
    if (doPool) {
        #pragma unroll
        for (int s = 0; s < 2; ++s)
            #pragma unroll
            for (int j = 0; j < 2; ++j)
                atomicAdd(&spool[s][wc * 32 + j * 16 + m15], ps[s][j]);
        __syncthreads();
        if (tid < 2 * BN) {
            int slot = tid >> 6, colt = tid & 63;
            int b = bA + slot;
            int lastb = (row0 + BM - 1) / HW_;
            if (b <= lastb)                    // slot 1 only if tile spans batches
                atomicAdd(&pooled[(size_t)b * C_ + col0 + colt], spool[slot][colt]);
        }
    }
}

// ---------- gating MLP + softmax over anchors (pooled = raw column sums) ----------
// also re-zeroes its pooled row for the next target block (saves zero launches)
__global__ __launch_bounds__(256) void gate_kernel(float* __restrict__ pooled,
    const float* __restrict__ fc1w, const float* __restrict__ fc1b,
    const float* __restrict__ fc2w, const float* __restrict__ fc2b,
    int t, float* __restrict__ gates)
{
    __shared__ float sp[C_];
    __shared__ float sh2[2][HID_];
    __shared__ float sh[HID_];
    const int b = blockIdx.x, tid = threadIdx.x;

    float2 pv = *(const float2*)&pooled[b * C_ + 2 * tid];
    sp[2 * tid]     = pv.x * (1.f / 196.f);
    sp[2 * tid + 1] = pv.y * (1.f / 196.f);
    *(float2*)&pooled[b * C_ + 2 * tid] = make_float2(0.f, 0.f);  // ready for next target
    __syncthreads();

    // fc1: 2 threads per output (split C in halves), 256 iters each
    {
        int half = tid >> 7, hh = tid & 127;
        const float* w = fc1w + (size_t)t * C_ * HID_ + hh;
        float s = 0.f;
        int c0 = half * 256;
        for (int c = c0; c < c0 + 256; ++c) s += sp[c] * w[(size_t)c * HID_];
        sh2[half][hh] = s;
    }
    __syncthreads();
    if (tid < HID_) sh[tid] = gelu_f(sh2[0][tid] + sh2[1][tid] + fc1b[t * HID_ + tid]);
    __syncthreads();

    #pragma unroll
    for (int cc = 0; cc < 2; ++cc) {
        int c = tid + cc * 256;
        const float* w2 = fc2w + (size_t)t * HID_ * (3 * C_) + c;
        float l0 = fc2b[t * 3 * C_ + c];
        float l1 = fc2b[t * 3 * C_ + C_ + c];
        float l2 = fc2b[t * 3 * C_ + 2 * C_ + c];
        for (int j = 0; j < HID_; ++j) {
            float h = sh[j];
            const float* r = w2 + (size_t)j * 3 * C_;
            l0 += h * r[0];
            l1 += h * r[C_];
            l2 += h * r[2 * C_];
        }
        float m  = fmaxf(l0, fmaxf(l1, l2));
        float e0 = expf(l0 - m), e1 = expf(l1 - m), e2 = expf(l2 - m);
        float inv = 1.f / (e0 + e1 + e2);
        gates[(size_t)b * 3 * C_ + c]          = e0 * inv;
        gates[(size_t)b * 3 * C_ + C_ + c]     = e1 * inv;
        gates[(size_t)b * 3 * C_ + 2 * C_ + c] = e2 * inv;
    }
}

// ---------- nx += gamma * sum_a gates[b,a,c]*anchor_a ; t==2 also writes fp32 out ----------
// x8 vectorized: 16B f16 loads from 4 activation arrays (64 B/thread)
__global__ __launch_bounds__(256) void routed_add_kernel(f16* __restrict__ nx,
    const f16* __restrict__ a0, const f16* __restrict__ a1, const f16* __restrict__ a2,
    const float* __restrict__ gates, const float* __restrict__ gammas, int t,
    float* __restrict__ outf)
{
    int v = blockIdx.x * 256 + threadIdx.x;    // vector index (8 elems each)
    int idx = v * 8;
    int c = idx & (C_ - 1);
    int b = idx / (HW_ * C_);
    const float* g = gates + (size_t)b * 3 * C_ + c;
    float gamma = gammas[t];
    f16x8 xn = ((const f16x8*)nx)[v];
    f16x8 x0 = ((const f16x8*)a0)[v];
    f16x8 x1 = ((const f16x8*)a1)[v];
    f16x8 x2 = ((const f16x8*)a2)[v];
    float r[8];
    #pragma unroll
    for (int e = 0; e < 8; ++e)
        r[e] = (float)xn[e] + gamma * (g[e] * (float)x0[e] + g[C_ + e] * (float)x1[e]
                                       + g[2 * C_ + e] * (float)x2[e]);
    if (outf) {
        float4* o = (float4*)&outf[idx];
        o[0] = make_float4(r[0], r[1], r[2], r[3]);
        o[1] = make_float4(r[4], r[5], r[6], r[7]);
    } else {
        f16x8 o;
        #pragma unroll
        for (int e = 0; e < 8; ++e) o[e] = (f16)r[e];
        ((f16x8*)nx)[v] = o;
    }
}

extern "C" void kernel_launch(void* const* d_in, const int* in_sizes, int n_in,
                              void* d_out, int out_size, void* d_ws, size_t ws_size,
                              hipStream_t stream)
{
    const float* x      = (const float*)d_in[0];
    const float* blockw = (const float*)d_in[1];
    const float* blockb = (const float*)d_in[2];
    const float* fc1w   = (const float*)d_in[3];
    const float* fc1b   = (const float*)d_in[4];
    const float* fc2w   = (const float*)d_in[5];
    const float* fc2b   = (const float*)d_in[6];
    const float* gammas = (const float*)d_in[7];
    float* out = (float*)d_out;

    const size_t NB = (size_t)M_ * C_;            // 3,211,264 elems/activation
    f16* Wt = (f16*)d_ws;                          // 18*512*512 halfs = 9.44MB
    f16* P0 = Wt + (size_t)NBLK * C_ * C_;
    f16* P1 = P0 + NB;
    f16* A0 = P0 + 2 * NB;
    f16* A1 = P0 + 3 * NB;
    f16* A2 = P0 + 4 * NB;
    float* pooled = (float*)(P0 + 5 * NB);         // 32*512 fp32 raw column sums
    float* gates  = pooled + B_ * C_;

    conv_w<<<dim3(8, 8, NBLK), 256, 0, stream>>>(blockw, Wt);
    conv_x<<<(int)(NB / 1024), 256, 0, stream>>>(x, P1, pooled);

    // x(fp16)=P1 feeds block 0; anchors (blocks 1,4,9 outputs) pinned A0/A1/A2
    const f16* ins[NBLK]  = {P1, P0, A0, P0, P1, A1, P0, P1, P0, P1, A2, P0, P1, P0, P1, P0, P1, P0};
    f16*       outs[NBLK] = {P0, A0, P0, P1, A1, P0, P1, P0, P1, A2, P0, P1, P0, P1, P0, P1, P0, P1};

    for (int i = 0; i < NBLK; ++i) {
        int t = (i == 11) ? 0 : (i == 14) ? 1 : (i == 17) ? 2 : -1;
        gemm_f16<<<dim3(M_ / BM, C_ / BN), 256, 0, stream>>>(
            ins[i], Wt, blockb, i, outs[i], (t >= 0) ? pooled : (float*)nullptr);
        if (t >= 0) {
            gate_kernel<<<B_, 256, 0, stream>>>(pooled, fc1w, fc1b, fc2w, fc2b, t, gates);
            routed_add_kernel<<<(int)(NB / 2048), 256, 0, stream>>>(
                outs[i], A0, A1, A2, gates, gammas, t,
                (t == 2) ? out : (float*)nullptr);
        }
    }
}

// Round 13
// 352.902 us; speedup vs baseline: 8.2812x; 1.1099x over previous
//
#include <hip/hip_runtime.h>

#define B_   32
#define HW_  196
#define C_   512
#define M_   (B_*HW_)    // 6272
#define HID_ 128
#define NBLK 18

typedef _Float16 f16;
typedef _Float16 f16x2 __attribute__((ext_vector_type(2)));
typedef _Float16 f16x4 __attribute__((ext_vector_type(4)));
typedef _Float16 f16x8 __attribute__((ext_vector_type(8)));
typedef float    f32x4 __attribute__((ext_vector_type(4)));

__device__ __forceinline__ float gelu_f(float x) {
    float t = tanhf(0.7978845608028654f * (x + 0.044715f * x * x * x));
    return 0.5f * x * (1.0f + t);
}

// async global->LDS, 16B per lane; LDS dest = wave-uniform base + lane*16
__device__ __forceinline__ void gl16(const void* g, void* l) {
    __builtin_amdgcn_global_load_lds((const __attribute__((address_space(1))) unsigned*)g,
                                     (__attribute__((address_space(3))) unsigned*)l, 16, 0, 0);
}

// ---------- merged prologue: x fp32->fp16 (+ zero 3 pooled bufs) AND W transpose ----------
// jobs [0,3136): conv_x; first 192 also zero pooled[3][32][512].
// jobs [3136,4288): conv_w 64x64 tile (blk = j/64, k0 = ((j%64)>>3)*64, n0 = (j%8)*64).
__global__ __launch_bounds__(256) void conv_xw(const float* __restrict__ in,
                                               f16* __restrict__ xout,
                                               float* __restrict__ pooled3,
                                               const float* __restrict__ W,
                                               f16* __restrict__ Wt) {
    __shared__ f16 sh[64][72];
    const int bid = blockIdx.x, tid = threadIdx.x;
    if (bid < 3136) {
        int i = bid * 256 + tid;
        if (bid < 192) pooled3[i] = 0.f;        // 192*256 = 3*32*512
        float4 a = ((const float4*)in)[i];
        f16x4 o; o[0] = (f16)a.x; o[1] = (f16)a.y; o[2] = (f16)a.z; o[3] = (f16)a.w;
        ((f16x4*)xout)[i] = o;
        return;
    }
    const int wjob = bid - 3136;
    const int blk = wjob >> 6, rem = wjob & 63;
    const int k0 = (rem >> 3) << 6, n0 = (rem & 7) << 6;
    const float* Wb = W + (size_t)blk * C_ * C_;
    #pragma unroll
    for (int i = 0; i < 4; ++i) {
        int s = tid + i * 256, r = s >> 4, c4 = (s & 15) << 2;
        float4 v = *(const float4*)&Wb[(size_t)(k0 + r) * C_ + n0 + c4];
        sh[r][c4 + 0] = (f16)v.x; sh[r][c4 + 1] = (f16)v.y;
        sh[r][c4 + 2] = (f16)v.z; sh[r][c4 + 3] = (f16)v.w;
    }
    __syncthreads();
    #pragma unroll
    for (int i = 0; i < 2; ++i) {
        int s = tid + i * 256, r = s >> 3, c8 = (s & 7) << 3;
        f16x8 o;
        #pragma unroll
        for (int j = 0; j < 8; ++j) o[j] = sh[c8 + j][r];
        *(f16x8*)&Wt[(size_t)blk * C_ * C_ + (size_t)(n0 + r) * C_ + k0 + c8] = o;
    }
}

// ---------- MFMA GEMM: out = gelu(A[M,K]@W_blk[K,N] + b) [+ column-sum pooling] ----------
// 64x64x64 tile, 4 waves. Proven best (r6 = 385.3us, reproduced r12 = 391.7us):
// 2-buffer 32KB LDS drain loop -> 4 blocks/CU (16 waves), grid 784 all-resident,
// chunked-XCD swizzle. Exploration record (r7-r11): fused routing 405, BM128 418,
// BN32 446, counted BK32 pipeline 395, persistent 1214, cooperative 2922.
#define BM 64
#define BN 64
#define BK 64
#define NKT (C_ / BK)   // 8
// LDS layout (halfs): tile[r][c-block] at r*64 + ((c ^ (r&7))<<3), r<64, c<8
__global__ __launch_bounds__(256, 4) void gemm_f16(
    const f16* __restrict__ A, const f16* __restrict__ Wt,
    const float* __restrict__ ball, int blk, f16* __restrict__ out,
    float* __restrict__ pooled)
{
    __shared__ f16 As[2][BM * BK];   // 2 x 8 KB
    __shared__ f16 Ws[2][BN * BK];   // 2 x 8 KB  -> 32 KB total, 4 blocks/CU
    __shared__ float spool[2][BN];   // per-batch-slot column sums (512 B)
    const int tid = threadIdx.x;
    const int wave = tid >> 6, lane = tid & 63;
    const int m15 = lane & 15, q = lane >> 4;
    const int wr = wave >> 1, wc = wave & 1;           // 2x2 wave grid, 32x32 tiles

    // chunked-XCD swizzle (bijective, 784 = 8*98)
    const int lin  = blockIdx.x + 98 * blockIdx.y;     // hw dispatch order
    const int tile = (lin & 7) * 98 + (lin >> 3);      // contiguous chunk per XCD
    const int rb   = tile >> 3, cb = tile & 7;
    const int row0 = rb * BM, col0 = cb * BN;

    const f16* Wb = Wt + (size_t)blk * C_ * C_;
    const float* bias = ball + (size_t)blk * C_;

    // staging: chunk ch = 8 rows x 64k (1KB). lane l loads row ch*8+(l>>3),
    // col-block (l&7)^(srow&7), landing at LDS base+l*16 = swizzled layout.
    const int srow = lane >> 3;
    const int scol = ((lane & 7) ^ (srow & 7)) << 3;   // halfs
    const f16* aSrc[2]; const f16* wSrc[2];
    f16* aDst[2][2]; f16* wDst[2][2];
    #pragma unroll
    for (int i = 0; i < 2; ++i) {
        int ch = wave * 2 + i;                          // 8 chunks cover 64 rows
        aSrc[i] = A  + (size_t)(row0 + ch * 8 + srow) * C_ + scol;
        wSrc[i] = Wb + (size_t)(col0 + ch * 8 + srow) * C_ + scol;
        aDst[0][i] = &As[0][ch * 512]; aDst[1][i] = &As[1][ch * 512];
        wDst[0][i] = &Ws[0][ch * 512]; wDst[1][i] = &Ws[1][ch * 512];
    }

    f32x4 acc[2][2];
    #pragma unroll
    for (int i = 0; i < 2; ++i)
        #pragma unroll
        for (int j = 0; j < 2; ++j) acc[i][j] = (f32x4)0.f;

    // prefetch tile 0 -> buf 0
    #pragma unroll
    for (int i = 0; i < 2; ++i) { gl16(aSrc[i], aDst[0][i]); gl16(wSrc[i], wDst[0][i]); }

    #pragma unroll
    for (int kt = 0; kt < NKT; ++kt) {
        __syncthreads();   // drains this tile's loads + syncs buffer reuse
        int cur = kt & 1;
        if (kt + 1 < NKT) {
            int nxt = cur ^ 1, koff = (kt + 1) * BK;
            #pragma unroll
            for (int i = 0; i < 2; ++i) {
                gl16(aSrc[i] + koff, aDst[nxt][i]);
                gl16(wSrc[i] + koff, wDst[nxt][i]);
            }
        }
        const f16* Ab = &As[cur][0];
        const f16* Bb = &Ws[cur][0];
        #pragma unroll
        for (int kk = 0; kk < BK; kk += 32) {
            f16x8 af[2], bf[2];
            #pragma unroll
            for (int i = 0; i < 2; ++i) {
                int r = wr * 32 + i * 16 + m15;
                int c = (kk >> 3) + q;
                af[i] = *(const f16x8*)&Ab[r * 64 + ((c ^ (r & 7)) << 3)];
            }
            #pragma unroll
            for (int j = 0; j < 2; ++j) {
                int r = wc * 32 + j * 16 + m15;
                int c = (kk >> 3) + q;
                bf[j] = *(const f16x8*)&Bb[r * 64 + ((c ^ (r & 7)) << 3)];
            }
            __builtin_amdgcn_s_setprio(1);
            #pragma unroll
            for (int i = 0; i < 2; ++i)
                #pragma unroll
                for (int j = 0; j < 2; ++j)
                    acc[i][j] = __builtin_amdgcn_mfma_f32_16x16x32_f16(af[i], bf[j], acc[i][j], 0, 0, 0);
            __builtin_amdgcn_s_setprio(0);
        }
    }

    // epilogue: C/D layout col=lane&15, row=quad*4+reg (HW-verified, dtype-indep)
    const bool doPool = (pooled != nullptr);
    if (doPool) {
        if (tid < 2 * BN) ((float*)spool)[tid] = 0.f;
        __syncthreads();
    }
    const int bA = row0 / HW_;                 // first batch this tile touches
    float ps[2][2] = {{0.f, 0.f}, {0.f, 0.f}}; // [batch-slot][j] partial sums
    float bcol[2];
    #pragma unroll
    for (int j = 0; j < 2; ++j) bcol[j] = bias[col0 + wc * 32 + j * 16 + m15];
    #pragma unroll
    for (int i = 0; i < 2; ++i) {
        #pragma unroll
        for (int r = 0; r < 4; ++r) {
            int rloc = wr * 32 + i * 16 + q * 4 + r;
            int row = row0 + rloc;
            int slot = (row / HW_) - bA;       // 0 or 1 (tile spans <= 2 batches)
            #pragma unroll
            for (int j = 0; j < 2; ++j) {
                int col = col0 + wc * 32 + j * 16 + m15;
                float v = gelu_f(acc[i][j][r] + bcol[j]);
                out[(size_t)row * C_ + col] = (f16)v;
                if (doPool) ps[slot & 1][j] += v;
            }
        }
    }
    if (doPool) {
        #pragma unroll
        for (int s = 0; s < 2; ++s)
            #pragma unroll
            for (int j = 0; j < 2; ++j)
                atomicAdd(&spool[s][wc * 32 + j * 16 + m15], ps[s][j]);
        __syncthreads();
        if (tid < 2 * BN) {
            int slot = tid >> 6, colt = tid & 63;
            int b = bA + slot;
            int lastb = (row0 + BM - 1) / HW_;
            if (b <= lastb)                    // slot 1 only if tile spans batches
                atomicAdd(&pooled[(size_t)b * C_ + col0 + colt], spool[slot][colt]);
        }
    }
}

// ---------- gating MLP + softmax over anchors (pooled = raw column sums) ----------
// grid (B_, 4): col-group cg owns 128 columns -> 128 blocks (4x parallelism of
// the old 32-block version; fc2 j-loop was the serial cost). fc1 replicated per
// group (identical split/order -> h bit-identical); per-column fc2/softmax math
// identical to the old kernel. pooled is a per-target buffer (no re-zero here —
// zeroed once in conv_xw; removes the cross-group write-after-read hazard).
__global__ __launch_bounds__(256) void gate_kernel(const float* __restrict__ pooled,
    const float* __restrict__ fc1w, const float* __restrict__ fc1b,
    const float* __restrict__ fc2w, const float* __restrict__ fc2b,
    int t, float* __restrict__ gates)
{
    __shared__ float sp[C_];
    __shared__ float sh2[2][HID_];
    __shared__ float sh[HID_];
    const int b = blockIdx.x, cg = blockIdx.y, tid = threadIdx.x;

    float2 pv = *(const float2*)&pooled[b * C_ + 2 * tid];
    sp[2 * tid]     = pv.x * (1.f / 196.f);
    sp[2 * tid + 1] = pv.y * (1.f / 196.f);
    __syncthreads();

    // fc1: 2 threads per output (split C in halves), 256 iters each
    {
        int half = tid >> 7, hh = tid & 127;
        const float* w = fc1w + (size_t)t * C_ * HID_ + hh;
        float s = 0.f;
        int c0 = half * 256;
        for (int c = c0; c < c0 + 256; ++c) s += sp[c] * w[(size_t)c * HID_];
        sh2[half][hh] = s;
    }
    __syncthreads();
    if (tid < HID_) sh[tid] = gelu_f(sh2[0][tid] + sh2[1][tid] + fc1b[t * HID_ + tid]);
    __syncthreads();

    if (tid < 128) {
        int c = cg * 128 + tid;
        const float* w2 = fc2w + (size_t)t * HID_ * (3 * C_) + c;
        float l0 = fc2b[t * 3 * C_ + c];
        float l1 = fc2b[t * 3 * C_ + C_ + c];
        float l2 = fc2b[t * 3 * C_ + 2 * C_ + c];
        for (int j = 0; j < HID_; ++j) {
            float h = sh[j];
            const float* r = w2 + (size_t)j * 3 * C_;
            l0 += h * r[0];
            l1 += h * r[C_];
            l2 += h * r[2 * C_];
        }
        float m  = fmaxf(l0, fmaxf(l1, l2));
        float e0 = expf(l0 - m), e1 = expf(l1 - m), e2 = expf(l2 - m);
        float inv = 1.f / (e0 + e1 + e2);
        gates[(size_t)b * 3 * C_ + c]          = e0 * inv;
        gates[(size_t)b * 3 * C_ + C_ + c]     = e1 * inv;
        gates[(size_t)b * 3 * C_ + 2 * C_ + c] = e2 * inv;
    }
}

// ---------- nx += gamma * sum_a gates[b,a,c]*anchor_a ; t==2 also writes fp32 out ----------
// x8 vectorized: 16B f16 loads from 4 activation arrays (64 B/thread)
__global__ __launch_bounds__(256) void routed_add_kernel(f16* __restrict__ nx,
    const f16* __restrict__ a0, const f16* __restrict__ a1, const f16* __restrict__ a2,
    const float* __restrict__ gates, const float* __restrict__ gammas, int t,
    float* __restrict__ outf)
{
    int v = blockIdx.x * 256 + threadIdx.x;    // vector index (8 elems each)
    int idx = v * 8;
    int c = idx & (C_ - 1);
    int b = idx / (HW_ * C_);
    const float* g = gates + (size_t)b * 3 * C_ + c;
    float gamma = gammas[t];
    f16x8 xn = ((const f16x8*)nx)[v];
    f16x8 x0 = ((const f16x8*)a0)[v];
    f16x8 x1 = ((const f16x8*)a1)[v];
    f16x8 x2 = ((const f16x8*)a2)[v];
    float r[8];
    #pragma unroll
    for (int e = 0; e < 8; ++e)
        r[e] = (float)xn[e] + gamma * (g[e] * (float)x0[e] + g[C_ + e] * (float)x1[e]
                                       + g[2 * C_ + e] * (float)x2[e]);
    if (outf) {
        float4* o = (float4*)&outf[idx];
        o[0] = make_float4(r[0], r[1], r[2], r[3]);
        o[1] = make_float4(r[4], r[5], r[6], r[7]);
    } else {
        f16x8 o;
        #pragma unroll
        for (int e = 0; e < 8; ++e) o[e] = (f16)r[e];
        ((f16x8*)nx)[v] = o;
    }
}

extern "C" void kernel_launch(void* const* d_in, const int* in_sizes, int n_in,
                              void* d_out, int out_size, void* d_ws, size_t ws_size,
                              hipStream_t stream)
{
    const float* x      = (const float*)d_in[0];
    const float* blockw = (const float*)d_in[1];
    const float* blockb = (const float*)d_in[2];
    const float* fc1w   = (const float*)d_in[3];
    const float* fc1b   = (const float*)d_in[4];
    const float* fc2w   = (const float*)d_in[5];
    const float* fc2b   = (const float*)d_in[6];
    const float* gammas = (const float*)d_in[7];
    float* out = (float*)d_out;

    const size_t NB = (size_t)M_ * C_;            // 3,211,264 elems/activation
    f16* Wt = (f16*)d_ws;                          // 18*512*512 halfs = 9.44MB
    f16* P0 = Wt + (size_t)NBLK * C_ * C_;
    f16* P1 = P0 + NB;
    f16* A0 = P0 + 2 * NB;
    f16* A1 = P0 + 3 * NB;
    f16* A2 = P0 + 4 * NB;
    float* pooled3 = (float*)(P0 + 5 * NB);        // [3][32][512] per-target column sums
    float* gates   = pooled3 + 3 * B_ * C_;

    conv_xw<<<3136 + 64 * NBLK, 256, 0, stream>>>(x, P1, pooled3, blockw, Wt);

    // x(fp16)=P1 feeds block 0; anchors (blocks 1,4,9 outputs) pinned A0/A1/A2
    const f16* ins[NBLK]  = {P1, P0, A0, P0, P1, A1, P0, P1, P0, P1, A2, P0, P1, P0, P1, P0, P1, P0};
    f16*       outs[NBLK] = {P0, A0, P0, P1, A1, P0, P1, P0, P1, A2, P0, P1, P0, P1, P0, P1, P0, P1};

    for (int i = 0; i < NBLK; ++i) {
        int t = (i == 11) ? 0 : (i == 14) ? 1 : (i == 17) ? 2 : -1;
        float* pooledT = (t >= 0) ? pooled3 + (size_t)t * B_ * C_ : (float*)nullptr;
        gemm_f16<<<dim3(M_ / BM, C_ / BN), 256, 0, stream>>>(
            ins[i], Wt, blockb, i, outs[i], pooledT);
        if (t >= 0) {
            gate_kernel<<<dim3(B_, 4), 256, 0, stream>>>(pooledT, fc1w, fc1b, fc2w, fc2b, t, gates);
            routed_add_kernel<<<(int)(NB / 2048), 256, 0, stream>>>(
                outs[i], A0, A1, A2, gates, gammas, t,
                (t == 2) ? out : (float*)nullptr);
        }
    }
}